// Round 9
// baseline (767.890 us; speedup 1.0000x reference)
//
#include <hip/hip_runtime.h>
#include <hip/hip_cooperative_groups.h>

// OccupancyGridForestAS — R12: cooperative fusion of the R11 two-phase split.
//
// R11 recap: phase1 (stream+XCD-bucket compaction) + phase2 (XCD-pinned sorted
// gathers) = 47 us/iter, vs monolith 42. Budget algebra: clean stream ~15 us
// (R8-K1), sorted gathers ~5-8 us (R10-p2) -> ~17 us unexplained, split unknown
// (both rows hidden < 40 us visibility floor). Suspects: launch gap, compaction
// machinery, cross-XCD out-scatter RMW.
//
// R12: ONE cooperative kernel, grid.sync() between phases.
//  * Kills the inter-kernel gap; yields ONE >=40us-visible dispatch row with
//    full FETCH/WRITE -- ends the blind algebra.
//  * __threadfence() (agent release/acquire: L2 wb+inv) around the sync makes
//    cross-XCD ent/cnt/out traffic correct on non-coherent L2s (G16).
//  * Grid exactly co-resident: 2048 blocks x 256 thr, launch_bounds(256,8)
//    (<=64 VGPR), 6.5 KB LDS -> 8 blocks/CU x 256 CU.
//  * Runtime fallback: if cooperative launch unavailable/rejected, run the
//    verbatim R11 two-kernel path (verified correct, 47 us).

#define LDIM 8
#define RES  64
#define NB   8    // buckets = XCDs

namespace cg = cooperative_groups;

typedef float v4f __attribute__((ext_vector_type(4)));

__device__ __forceinline__ void compute4(
    const int* __restrict__ slut, v4f q0, v4f q1, v4f q2,
    int ii[4], int tr[4], bool valid[4])
{
    const float xs[4] = {q0.x, q0.w, q1.z, q2.y};
    const float ys[4] = {q0.y, q1.x, q1.w, q2.z};
    const float zs[4] = {q0.z, q1.y, q2.x, q2.w};
#pragma unroll
    for (int k = 0; k < 4; ++k) {
        float x = xs[k], y = ys[k], z = zs[k];
        int bx = (int)floorf(x);
        int by = (int)floorf(y);
        int bz = (int)floorf(z);
        bool in_dom = (bx >= 0) & (bx < LDIM) &
                      (by >= 0) & (by < LDIM) &
                      (bz >= 0) & (bz < LDIM);
        int cx = min(max(bx, 0), LDIM - 1);
        int cy = min(max(by, 0), LDIM - 1);
        int cz = min(max(bz, 0), LDIM - 1);

        int bidx = slut[(cx * LDIM + cy) * LDIM + cz];
        bool v = in_dom & (bidx >= 0);

        // Reference float op sequence, replicated exactly.
        float bxf = 2.0f * (x - (float)cx) - 1.0f;
        float byf = 2.0f * (y - (float)cy) - 1.0f;
        float bzf = 2.0f * (z - (float)cz) - 1.0f;
        float tx = (bxf * 0.5f + 0.5f) * (float)RES;
        float ty = (byf * 0.5f + 0.5f) * (float)RES;
        float tz = (bzf * 0.5f + 0.5f) * (float)RES;
        int vx = min(max((int)floorf(tx), 0), RES - 1);
        int vy = min(max((int)floorf(ty), 0), RES - 1);
        int vz = min(max((int)floorf(tz), 0), RES - 1);

        int sb = v ? bidx : 0;
        ii[k] = ((sb * RES + vx) * RES + vy) * RES + vz;  // < 2^24
        tr[k] = sb;
        valid[k] = v;
    }
}

// ---------- Phase A body (stream + compact), shared by fused & split. ----------
template<int SCAP>
__device__ __forceinline__ void phaseA_body(
    const v4f* __restrict__ pts4, const float* __restrict__ grid,
    const int* __restrict__ lookup, v4f* __restrict__ out4,
    int* __restrict__ cnt, int2* __restrict__ ent, int T,
    int* slut, int2* staged, int* lcnt)
{
    ((int2*)slut)[threadIdx.x] = ((const int2*)lookup)[threadIdx.x];
    if (threadIdx.x < NB) lcnt[threadIdx.x] = 0;
    __syncthreads();  // before any global load: vmcnt drain is free

    int tid = threadIdx.x;
    int blk = blockIdx.x;
    int j = blk * 256 + tid;

    const v4f* pA = pts4 + 3 * j;
    v4f a0 = pA[0], a1 = pA[1], a2 = pA[2];
    const v4f* pB = pts4 + 3 * (j + T);
    v4f b0 = pB[0], b1 = pB[1], b2 = pB[2];

    {
        int ii[4], tr[4]; bool vv[4];
        compute4(slut, a0, a1, a2, ii, tr, vv);
        v4f oz = {0.0f, 0.0f, 0.0f, 0.0f};
#pragma unroll
        for (int k = 0; k < 4; ++k) {
            if (vv[k]) {
                int x = tr[k] & (NB - 1);
                int lp = atomicAdd(&lcnt[x], 1);
                if (lp < SCAP) staged[x * SCAP + lp] = make_int2(4 * j + k, ii[k]);
                else oz[k] = grid[ii[k]];   // ~6-sigma spill belt
            }
        }
        out4[j] = oz;
    }
    {
        int ii[4], tr[4]; bool vv[4];
        compute4(slut, b0, b1, b2, ii, tr, vv);
        v4f oz = {0.0f, 0.0f, 0.0f, 0.0f};
#pragma unroll
        for (int k = 0; k < 4; ++k) {
            if (vv[k]) {
                int x = tr[k] & (NB - 1);
                int lp = atomicAdd(&lcnt[x], 1);
                if (lp < SCAP) staged[x * SCAP + lp] = make_int2(4 * (j + T) + k, ii[k]);
                else oz[k] = grid[ii[k]];
            }
        }
        out4[j + T] = oz;
    }
    __syncthreads();

    // 8 contiguous SCAP-entry runs (coalesced, full lines) + counts.
    int nblk = gridDim.x;
    for (int i = tid; i < NB * SCAP; i += 256) {
        int x = i / SCAP, s = i % SCAP;
        ent[((size_t)x * nblk + blk) * SCAP + s] = staged[i];
    }
    if (tid < NB) cnt[blk * NB + tid] = min(lcnt[tid], SCAP);
}

// ---------- Phase B body (XCD-pinned sorted gather + scatter). ----------
template<int SCAP>
__device__ __forceinline__ void phaseB_body(
    const float* __restrict__ grid, const int* __restrict__ cnt,
    const int2* __restrict__ ent, float* __restrict__ out, int nblk)
{
    const int NPOS = NB * SCAP;
    int x = blockIdx.x & (NB - 1);        // bucket == XCD (blk%8 round-robin)
    int g = blockIdx.x >> 3;              // group of 8 phase-A blocks
    const int2* eb = ent + (size_t)x * nblk * SCAP + (size_t)g * NPOS;
    int t = threadIdx.x;

    int i0 = t, i1 = t + 256;
    bool q1 = i1 < NPOS;
    int2 e0 = eb[i0];
    int2 e1 = q1 ? eb[i1] : make_int2(0, 0);
    int c0 = cnt[(g * NB + i0 / SCAP) * NB + x];
    int c1 = q1 ? cnt[(g * NB + i1 / SCAP) * NB + x] : 0;
    bool p0 = (i0 % SCAP) < c0;
    bool p1 = q1 & ((i1 % SCAP) < c1);

    float v0 = grid[p0 ? e0.y : 0];
    float v1 = grid[p1 ? e1.y : 0];
    if (p0) out[e0.x] = v0;
    if (p1) out[e1.x] = v1;
}

// ---------- Fused cooperative kernel. ----------
template<int SCAP>
__global__ __launch_bounds__(256, 8) void fused_kernel(
    const v4f*   __restrict__ pts4,
    const float* __restrict__ grid,
    const int*   __restrict__ lookup,
    v4f*         __restrict__ out4,
    int*         __restrict__ cnt,
    int2*        __restrict__ ent,
    int T)
{
    __shared__ int  slut[LDIM * LDIM * LDIM];  // 2 KB
    __shared__ int2 staged[NB * SCAP];         // <= 4 KB
    __shared__ int  lcnt[NB];

    phaseA_body<SCAP>(pts4, grid, lookup, out4, cnt, ent, T, slut, staged, lcnt);

    // Device-scope release: flush dirty L2 (ent/cnt/out zeros) to L3.
    __threadfence();
    cg::this_grid().sync();
    // Device-scope acquire: invalidate L2 before reading other XCDs' data.
    __threadfence();

    phaseB_body<SCAP>(grid, cnt, ent, (float*)out4, gridDim.x);
}

// ---------- Split kernels (verbatim R11 fallback). ----------
template<int SCAP>
__global__ __launch_bounds__(256) void phase1_kernel(
    const v4f* __restrict__ pts4, const float* __restrict__ grid,
    const int* __restrict__ lookup, v4f* __restrict__ out4,
    int* __restrict__ cnt, int2* __restrict__ ent, int T)
{
    __shared__ int  slut[LDIM * LDIM * LDIM];
    __shared__ int2 staged[NB * SCAP];
    __shared__ int  lcnt[NB];
    phaseA_body<SCAP>(pts4, grid, lookup, out4, cnt, ent, T, slut, staged, lcnt);
}

template<int SCAP>
__global__ __launch_bounds__(256) void phase2_kernel(
    const float* __restrict__ grid, const int* __restrict__ cnt,
    const int2* __restrict__ ent, float* __restrict__ out, int nblk1)
{
    phaseB_body<SCAP>(grid, cnt, ent, out, nblk1);
}

// ---------- No-workspace fallback: R7 pipelined monolith. ----------
__global__ __launch_bounds__(256, 8) void occ_forest_fallback(
    const v4f* __restrict__ pts4, const float* __restrict__ grid,
    const int* __restrict__ lookup, v4f* __restrict__ out4, int T)
{
    __shared__ int slut[LDIM * LDIM * LDIM];
    ((int2*)slut)[threadIdx.x] = ((const int2*)lookup)[threadIdx.x];
    __syncthreads();
    int j = blockIdx.x * blockDim.x + threadIdx.x;
    const v4f* pA = pts4 + 3 * j;
    v4f a0 = pA[0], a1 = pA[1], a2 = pA[2];
    const v4f* pB = pts4 + 3 * (j + T);
    v4f b0 = pB[0], b1 = pB[1], b2 = pB[2];

    int iiA[4], trA[4]; bool vA[4];
    compute4(slut, a0, a1, a2, iiA, trA, vA);
    float gA[4];
#pragma unroll
    for (int k = 0; k < 4; ++k) gA[k] = grid[vA[k] ? iiA[k] : 0];
    int iiB[4], trB[4]; bool vB[4];
    compute4(slut, b0, b1, b2, iiB, trB, vB);
    float gB[4];
#pragma unroll
    for (int k = 0; k < 4; ++k) gB[k] = grid[vB[k] ? iiB[k] : 0];

    v4f oA, oB;
#pragma unroll
    for (int k = 0; k < 4; ++k) oA[k] = vA[k] ? gA[k] : 0.0f;
#pragma unroll
    for (int k = 0; k < 4; ++k) oB[k] = vB[k] ? gB[k] : 0.0f;
    out4[j] = oA;
    out4[j + T] = oB;
}

extern "C" void kernel_launch(void* const* d_in, const int* in_sizes, int n_in,
                              void* d_out, int out_size, void* d_ws, size_t ws_size,
                              hipStream_t stream) {
    const float* pts    = (const float*)d_in[0];
    const float* grid   = (const float*)d_in[1];
    const int*   lookup = (const int*)d_in[2];

    int T = out_size / 8;                      // 524288 threads, 8 pts each
    int threads = 256;
    int nblk = T / threads;                    // 2048 (exact)

    size_t cnt_b = (size_t)nblk * NB * sizeof(int);  // 64 KB
    auto ent_b = [&](int scap) { return (size_t)NB * nblk * scap * sizeof(int2); };

    static int coop = -1;   // host-side query, capture-safe (no stream op)
    if (coop < 0) {
        int v = 0;
        hipDeviceGetAttribute(&v, hipDeviceAttributeCooperativeLaunch, 0);
        coop = v;
    }

    int scap = 0;
    if (d_ws && ws_size >= cnt_b + ent_b(64)) scap = 64;       // 8.06 MB
    else if (d_ws && ws_size >= cnt_b + ent_b(48)) scap = 48;  // 6.06 MB

    if (scap == 0) {
        occ_forest_fallback<<<nblk, threads, 0, stream>>>(
            (const v4f*)pts, grid, lookup, (v4f*)d_out, T);
        return;
    }

    int*  cnt = (int*)d_ws;
    int2* ent = (int2*)((char*)d_ws + cnt_b);

    if (coop) {
        const v4f* pts4a = (const v4f*)pts;
        v4f* out4a = (v4f*)d_out;
        void* args[] = { (void*)&pts4a, (void*)&grid, (void*)&lookup,
                         (void*)&out4a, (void*)&cnt, (void*)&ent, (void*)&T };
        hipError_t err;
        if (scap == 64) {
            err = hipLaunchCooperativeKernel((void*)fused_kernel<64>,
                dim3(nblk), dim3(threads), args, 0, stream);
        } else {
            err = hipLaunchCooperativeKernel((void*)fused_kernel<48>,
                dim3(nblk), dim3(threads), args, 0, stream);
        }
        if (err == hipSuccess) return;
        // else fall through to the split path (nothing was enqueued)
    }

    if (scap == 64) {
        phase1_kernel<64><<<nblk, threads, 0, stream>>>(
            (const v4f*)pts, grid, lookup, (v4f*)d_out, cnt, ent, T);
        phase2_kernel<64><<<nblk, threads, 0, stream>>>(
            grid, cnt, ent, (float*)d_out, nblk);
    } else {
        phase1_kernel<48><<<nblk, threads, 0, stream>>>(
            (const v4f*)pts, grid, lookup, (v4f*)d_out, cnt, ent, T);
        phase2_kernel<48><<<nblk, threads, 0, stream>>>(
            grid, cnt, ent, (float*)d_out, nblk);
    }
}

// Round 10
// 139.241 us; speedup vs baseline: 5.5148x; 5.5148x over previous
//
#include <hip/hip_runtime.h>

// OccupancyGridForestAS — R13: R7's 2-deep pipeline + R0's ordered grid sweep,
// combined in one wave program (the two only levers that ever won, +3 us each).
//
// R12 post-mortem: cooperative grid.sync() on 2048 blocks = ~600 us of spin
// (Occ 92%, VALU 1.1%, HBM 1.8%) -- coop + the whole compaction family dead.
//
// Consolidated model (10 structures, 42-47 us, byte-insensitive): per-CU
// outstanding-reads (~64 lines) x latency cap:
//   no sweep: (3072 pts-lines x 0.45us + ~1800 cold-gather-lines x 0.9us)/64 ~= 45 us
//   sweep+pipeline: (3072x0.45 + 1024x0.65(seq) + 1800x0.17(L3-hit))/64 ~= 34 us
// R0 proved the sweep (serial structure, and VGPR_Count=20 shows its sweep was
// register-serialized); R7 proved the pipeline. This kernel does both:
//  * pts loads (nt) issued FIRST; sweep (cached, 8 x float4, whole 64 MB across
//    the grid of threads) issued second. vmcnt is in-order -> idx-A's wait on
//    the older pts loads does NOT drain the newer sweeps; sweep latency hides
//    under pts-wait + idx ALU.
//  * sweep consumed via asm keepalive + "memory" clobber + sched_barrier(0)
//    BEFORE the first gather: per-wave sweep-before-gather ordering (the thing
//    whose absence sank the fire-and-forget R5), at ~zero VALU cost.
//  * launch_bounds(256,4): ~128 VGPR budget so all 14 loads stay in flight
//    (8 sweep float4 = 32 live VGPRs; at (256,8)'s 64-VGPR cap the compiler
//    would re-serialize the sweep exactly like R0).
//  * nt pts loads / out stores (must not evict grid from L3); sweep cached.

#define LDIM 8
#define RES  64

typedef float v4f __attribute__((ext_vector_type(4)));

// Compute gather indices for 4 points packed in 3 float4s.
// Float op sequence replicated exactly from the reference.
__device__ __forceinline__ void compute_idx4(
    const int* __restrict__ slut, v4f q0, v4f q1, v4f q2,
    int idx[4], bool valid[4])
{
    const float xs[4] = {q0.x, q0.w, q1.z, q2.y};
    const float ys[4] = {q0.y, q1.x, q1.w, q2.z};
    const float zs[4] = {q0.z, q1.y, q2.x, q2.w};
#pragma unroll
    for (int k = 0; k < 4; ++k) {
        float x = xs[k], y = ys[k], z = zs[k];

        int bx = (int)floorf(x);
        int by = (int)floorf(y);
        int bz = (int)floorf(z);
        bool in_dom = (bx >= 0) & (bx < LDIM) &
                      (by >= 0) & (by < LDIM) &
                      (bz >= 0) & (bz < LDIM);
        int cx = min(max(bx, 0), LDIM - 1);
        int cy = min(max(by, 0), LDIM - 1);
        int cz = min(max(bz, 0), LDIM - 1);

        int bidx = slut[(cx * LDIM + cy) * LDIM + cz];
        bool v = in_dom & (bidx >= 0);

        float bxf = 2.0f * (x - (float)cx) - 1.0f;
        float byf = 2.0f * (y - (float)cy) - 1.0f;
        float bzf = 2.0f * (z - (float)cz) - 1.0f;
        float tx = (bxf * 0.5f + 0.5f) * (float)RES;
        float ty = (byf * 0.5f + 0.5f) * (float)RES;
        float tz = (bzf * 0.5f + 0.5f) * (float)RES;
        int vx = min(max((int)floorf(tx), 0), RES - 1);
        int vy = min(max((int)floorf(ty), 0), RES - 1);
        int vz = min(max((int)floorf(tz), 0), RES - 1);

        int sb = v ? bidx : 0;
        int ii = ((sb * RES + vx) * RES + vy) * RES + vz;  // < 2^24
        idx[k]   = v ? ii : 0;   // invalid -> grid[0]: same-line broadcast
        valid[k] = v;
    }
}

__global__ __launch_bounds__(256, 4) void occ_forest_kernel(
    const v4f*    __restrict__ pts4,
    const float*  __restrict__ grid,
    const int*    __restrict__ lookup,
    v4f*          __restrict__ out4,
    int T)        // total threads; thread j handles 4-pt chunks j and j+T
{
    __shared__ int slut[LDIM * LDIM * LDIM];  // 512 ints = 2 KB

    ((int2*)slut)[threadIdx.x] = ((const int2*)lookup)[threadIdx.x];
    // Barrier BEFORE any global load: its vmcnt(0) drain costs nothing.
    __syncthreads();

    int j = blockIdx.x * blockDim.x + threadIdx.x;

    // --- pts loads first (oldest in vmcnt order), nontemporal. ---
    const v4f* pA = pts4 + 3 * j;
    v4f a0 = __builtin_nontemporal_load(pA + 0);
    v4f a1 = __builtin_nontemporal_load(pA + 1);
    v4f a2 = __builtin_nontemporal_load(pA + 2);
    const v4f* pB = pts4 + 3 * (j + T);
    v4f b0 = __builtin_nontemporal_load(pB + 0);
    v4f b1 = __builtin_nontemporal_load(pB + 1);
    v4f b2 = __builtin_nontemporal_load(pB + 2);

    // --- Grid sweep second (newer): 8 cached float4, strided by T.
    // 524288 threads x 8 x 16B = 64 MiB = the whole grid, exactly in bounds
    // (max index = 524287 + 7*524288 = 4194303 = last float4 of the grid).
    const v4f* g4 = (const v4f*)grid;
    v4f s0 = g4[j + 0 * T];
    v4f s1 = g4[j + 1 * T];
    v4f s2 = g4[j + 2 * T];
    v4f s3 = g4[j + 3 * T];
    v4f s4 = g4[j + 4 * T];
    v4f s5 = g4[j + 5 * T];
    v4f s6 = g4[j + 6 * T];
    v4f s7 = g4[j + 7 * T];

    // --- idx A: waits only on a0..a2 (older than the sweeps; in-order vmcnt).
    int idxA[4]; bool valA[4];
    compute_idx4(slut, a0, a1, a2, idxA, valA);

    // --- Sweep fence: my sweep slice is L3-resident before my gathers issue.
    // "memory" clobber + sched_barrier(0) stop the compiler from hoisting the
    // gathers above this point (asm alone does not order memory ops).
    asm volatile("" :: "v"(s0), "v"(s1), "v"(s2), "v"(s3),
                       "v"(s4), "v"(s5), "v"(s6), "v"(s7) : "memory");
    __builtin_amdgcn_sched_barrier(0);

    // --- Gathers A in flight; idx B ALU overlaps their latency. ---
    float vA[4];
#pragma unroll
    for (int k = 0; k < 4; ++k) vA[k] = grid[idxA[k]];

    int idxB[4]; bool valB[4];
    compute_idx4(slut, b0, b1, b2, idxB, valB);

    float vB[4];
#pragma unroll
    for (int k = 0; k < 4; ++k) vB[k] = grid[idxB[k]];

    // --- Store A (waits vmcnt(4): B-gathers stay in flight), then B. ---
#pragma unroll
    for (int k = 0; k < 4; ++k) vA[k] = valA[k] ? vA[k] : 0.0f;
    v4f oA = {vA[0], vA[1], vA[2], vA[3]};
    __builtin_nontemporal_store(oA, out4 + j);

#pragma unroll
    for (int k = 0; k < 4; ++k) vB[k] = valB[k] ? vB[k] : 0.0f;
    v4f oB = {vB[0], vB[1], vB[2], vB[3]};
    __builtin_nontemporal_store(oB, out4 + j + T);
}

extern "C" void kernel_launch(void* const* d_in, const int* in_sizes, int n_in,
                              void* d_out, int out_size, void* d_ws, size_t ws_size,
                              hipStream_t stream) {
    const float* pts    = (const float*)d_in[0];
    const float* grid   = (const float*)d_in[1];
    const int*   lookup = (const int*)d_in[2];
    float*       out    = (float*)d_out;

    // out_size = 4194304 points; 8 points per thread as 2 pipelined groups of 4.
    int T = out_size / 8;                       // 524288 threads
    int threads = 256;
    int blocks = (T + threads - 1) / threads;   // 2048 blocks
    occ_forest_kernel<<<blocks, threads, 0, stream>>>(
        (const v4f*)pts, grid, lookup, (v4f*)out, T);
}